// Round 22
// baseline (1492.325 us; speedup 1.0000x reference)
//
#include <hip/hip_runtime.h>
#include <hip/hip_fp16.h>

#define N_NODES 25000   // = 3125 * 8 exactly
#define E_EDGES 400000
#define KM 200      // message channels
#define RS 224      // A-row stride (floats): 200 fp32 A | 20 fp32 x | pad (896 B)
#define RSB 256     // B-row stride BYTES: 200 int8 | pad | 20 fp16 x @208 | inv_p,inv_x @248

typedef float v2f __attribute__((ext_vector_type(2)));  // v_pk_fma_f32 operand

__device__ __forceinline__ float2 h2f(unsigned u) {
  return __half22float2(*(const __half2*)&u);
}
__device__ __forceinline__ float4 i8x4f(unsigned u) {
  float4 f;
  f.x = (float)((int)(u << 24) >> 24);
  f.y = (float)((int)(u << 16) >> 24);
  f.z = (float)((int)(u << 8) >> 24);
  f.w = (float)((int)u >> 24);
  return f;
}
// bf16 round-half-up pack / unpack (gd is bf16 to halve its HBM round-trip)
__device__ __forceinline__ unsigned short f2bfr(float v) {
  unsigned u = __float_as_uint(v) + 0x8000u;
  return (unsigned short)(u >> 16);
}
__device__ __forceinline__ float bf2f(unsigned short h) {
  return __uint_as_float((unsigned)h << 16);
}

// Segment sum with batched loads: 8 loads in flight, adds in original order
// (single accumulator, sequential) -> bitwise-identical to the naive loop.
__device__ __forceinline__ float seg_sum_bf16(const unsigned short* __restrict__ g,
                                              int s, int t) {
  float v = 0.f;
  int e = s;
  int t8 = s + ((t - s) & ~7);
  for (; e < t8; e += 8) {
    unsigned short u0 = g[e + 0], u1 = g[e + 1], u2 = g[e + 2], u3 = g[e + 3];
    unsigned short u4 = g[e + 4], u5 = g[e + 5], u6 = g[e + 6], u7 = g[e + 7];
    v += bf2f(u0); v += bf2f(u1); v += bf2f(u2); v += bf2f(u3);
    v += bf2f(u4); v += bf2f(u5); v += bf2f(u6); v += bf2f(u7);
  }
  int t2 = s + ((t - s) & ~1);
  for (; e < t2; e += 2) {
    unsigned short u0 = g[e + 0], u1 = g[e + 1];
    v += bf2f(u0); v += bf2f(u1);
  }
  if (e < t) v += bf2f(g[e]);
  return v;
}

// ---------------- sort-by-dst (CSR build) ----------------

__global__ void hist_kernel(const int* __restrict__ edges, int* __restrict__ hist) {
  int e = blockIdx.x * blockDim.x + threadIdx.x;
  if (e < E_EDGES) atomicAdd(&hist[edges[E_EDGES + e]], 1);
}

__global__ void scan_kernel(const int* __restrict__ hist, int* __restrict__ off,
                            int* __restrict__ cursor) {
  __shared__ int sums[1024];
  const int CH = (N_NODES + 1023) / 1024;  // 25
  int tid = threadIdx.x;
  int base = tid * CH;
  int s = 0;
  for (int i = 0; i < CH; i++) {
    int idx = base + i;
    if (idx < N_NODES) s += hist[idx];
  }
  sums[tid] = s;
  __syncthreads();
  for (int d = 1; d < 1024; d <<= 1) {
    int v = (tid >= d) ? sums[tid - d] : 0;
    __syncthreads();
    sums[tid] += v;
    __syncthreads();
  }
  int run = (tid == 0) ? 0 : sums[tid - 1];
  for (int i = 0; i < CH; i++) {
    int idx = base + i;
    if (idx < N_NODES) {
      off[idx] = run;
      cursor[idx] = run;
      run += hist[idx];
    }
  }
  if (tid == 1023) off[N_NODES] = run;  // == E
}

// ---------------- per-layer kernels ----------------

// Fused: scatter (128 edges/block) + prep layer-d (8 nodes/block) + d_out zeroing.
// prep: A fp32; B int8 (exact bound: max_k |x*wb_k| = |x|*wbmax); x-tail fp16.
__global__ void __launch_bounds__(256) scatter_prep_d_kernel(
    const int* __restrict__ edges, int* __restrict__ cursor, int2* __restrict__ se,
    const float* __restrict__ xin,
    const float* __restrict__ Wm1, const float* __restrict__ bm1,
    float* __restrict__ A2, unsigned char* __restrict__ Bq, float* __restrict__ xr,
    float* __restrict__ out) {
  int tid = threadIdx.x;
  // d_out zeroing (edge_final accumulates atomically): 3125 * 8 = 25000 exactly
  if (tid < 8) out[blockIdx.x * 8 + tid] = 0.f;
  // scatter part: 3125 * 128 = 400000 exactly
  if (tid < 128) {
    int e = blockIdx.x * 128 + tid;
    int s = edges[e];
    int d = edges[E_EDGES + e];
    int pos = atomicAdd(&cursor[d], 1);
    se[pos] = make_int2(s, d);
  }
  // prep part
  __shared__ unsigned wbmaxu;
  if (tid == 0) wbmaxu = 0;
  __syncthreads();
  int k = tid;
  float wa = 0.f, wb = 0.f, bm = 0.f;
  if (k < KM) {
    bm = bm1[k];
    wa = Wm1[k];
    wb = Wm1[KM + k];
  }
  float mb = (k < KM) ? fabsf(wb) : 0.f;
#pragma unroll
  for (int s = 1; s < 64; s <<= 1) mb = fmaxf(mb, __shfl_xor(mb, s));
  if ((k & 63) == 0) atomicMax(&wbmaxu, __float_as_uint(mb));
  __syncthreads();
  float wbmax = fmaxf(__uint_as_float(wbmaxu), 1e-30f);
  int n0 = blockIdx.x * 8;
  for (int i = 0; i < 8; i++) {
    int n = n0 + i;
    float xv = xin[n];
    float bBound = fmaxf(fabsf(xv) * wbmax, 1e-30f);
    float xBound = fmaxf(fabsf(xv), 1e-30f);
    size_t rowA = (size_t)n * RS;
    unsigned char* rb = Bq + (size_t)n * RSB;
    if (k == 0) {
      xr[n] = xv;
      A2[rowA + KM] = xv;
      ((__half*)(rb + 208))[0] = __float2half(xv * (32768.f / xBound));
      ((float*)(rb + 248))[0] = bBound / 127.f;
      ((float*)(rb + 248))[1] = xBound / 32768.f;
    }
    if (k < KM) {
      A2[rowA + k] = bm + xv * wa;
      rb[k] = (unsigned char)(signed char)lrintf(xv * wb * (127.f / bBound));
    }
  }
}

// Edge kernel, 2 THREADS PER EDGE: thread (e, half) handles the even/odd
// 16-byte chunks of the B-row (k0 = 32j + 16*half, j=0..5; half0 also takes
// the k=192..199 tail). Lane pairs hit the same cache line per load instr
// (coalesced, FETCH unchanged) while the per-thread chain halves and the
// grid doubles to 6250 blocks -> ~2x waves for latency hiding.
// Partial gates combine via shfl_xor (commutative fp add, deterministic);
// even lane does x-diff + bf16 nt-stores.
template <int CIN>
__global__ void __launch_bounds__(128) edge_kernel(
    const int2* __restrict__ se,
    const float* __restrict__ A2, const unsigned char* __restrict__ Bq,
    const float* __restrict__ Wm2, const float* __restrict__ bm2,
    unsigned short* __restrict__ gd) {
  int t = threadIdx.x;
  int e = blockIdx.x * 64 + (t >> 1);  // grid exact: 6250 * 64 = 400000
  int half = t & 1;
  int2 sd = se[e];
  int src = sd.x;
  int dst = sd.y;
  const float* Ar = A2 + (size_t)dst * RS;
  const unsigned char* Br = Bq + (size_t)src * RSB;
  float invB = ((const float*)(Br + 248))[0];
  constexpr int NP = (CIN + 1) / 2;
  v2f gate2[NP];
  if constexpr (CIN == 20) {
#pragma unroll
    for (int i = 0; i < NP; i++) {
      if (half == 0) {
        gate2[i] = *(const v2f*)(bm2 + 2 * i);
      } else {
        gate2[i].x = 0.f;
        gate2[i].y = 0.f;
      }
    }
  } else {
    gate2[0].x = (half == 0) ? bm2[0] : 0.f;
    gate2[0].y = 0.f;
  }
  // 6 iterations of 16 channels each: k0 = 32j + 16*half (192 channels total)
#pragma unroll 2
  for (int j = 0; j < 6; j++) {
    int k0 = 32 * j + 16 * half;
    float4 a0 = *(const float4*)(Ar + k0);
    float4 a1 = *(const float4*)(Ar + k0 + 4);
    float4 a2 = *(const float4*)(Ar + k0 + 8);
    float4 a3 = *(const float4*)(Ar + k0 + 12);
    uint4 braw = *(const uint4*)(Br + k0);  // 16 int8
    float4 f0 = i8x4f(braw.x);
    float4 f1 = i8x4f(braw.y);
    float4 f2 = i8x4f(braw.z);
    float4 f3 = i8x4f(braw.w);
    float h[16];
    h[0] = fmaxf(a0.x + f0.x * invB, 0.f);
    h[1] = fmaxf(a0.y + f0.y * invB, 0.f);
    h[2] = fmaxf(a0.z + f0.z * invB, 0.f);
    h[3] = fmaxf(a0.w + f0.w * invB, 0.f);
    h[4] = fmaxf(a1.x + f1.x * invB, 0.f);
    h[5] = fmaxf(a1.y + f1.y * invB, 0.f);
    h[6] = fmaxf(a1.z + f1.z * invB, 0.f);
    h[7] = fmaxf(a1.w + f1.w * invB, 0.f);
    h[8] = fmaxf(a2.x + f2.x * invB, 0.f);
    h[9] = fmaxf(a2.y + f2.y * invB, 0.f);
    h[10] = fmaxf(a2.z + f2.z * invB, 0.f);
    h[11] = fmaxf(a2.w + f2.w * invB, 0.f);
    h[12] = fmaxf(a3.x + f3.x * invB, 0.f);
    h[13] = fmaxf(a3.y + f3.y * invB, 0.f);
    h[14] = fmaxf(a3.z + f3.z * invB, 0.f);
    h[15] = fmaxf(a3.w + f3.w * invB, 0.f);
    if constexpr (CIN == 20) {
#pragma unroll
      for (int jj = 0; jj < 16; jj++) {
        v2f hj;
        hj.x = h[jj];
        hj.y = h[jj];
        const v2f* w2 = (const v2f*)(Wm2 + (k0 + jj) * 20);
#pragma unroll
        for (int i = 0; i < 10; i++) gate2[i] += hj * w2[i];
      }
    } else {
      float g = gate2[0].x;
#pragma unroll
      for (int jj = 0; jj < 16; jj++) g += h[jj] * Wm2[k0 + jj];
      gate2[0].x = g;
    }
  }
  if (half == 0) {  // tail k = 192..199
    float4 a0 = *(const float4*)(Ar + 192);
    float4 a1 = *(const float4*)(Ar + 196);
    uint2 braw = *(const uint2*)(Br + 192);
    float4 f01 = i8x4f(braw.x);
    float4 f23 = i8x4f(braw.y);
    float h[8];
    h[0] = fmaxf(a0.x + f01.x * invB, 0.f);
    h[1] = fmaxf(a0.y + f01.y * invB, 0.f);
    h[2] = fmaxf(a0.z + f01.z * invB, 0.f);
    h[3] = fmaxf(a0.w + f01.w * invB, 0.f);
    h[4] = fmaxf(a1.x + f23.x * invB, 0.f);
    h[5] = fmaxf(a1.y + f23.y * invB, 0.f);
    h[6] = fmaxf(a1.z + f23.z * invB, 0.f);
    h[7] = fmaxf(a1.w + f23.w * invB, 0.f);
    if constexpr (CIN == 20) {
#pragma unroll
      for (int jj = 0; jj < 8; jj++) {
        v2f hj;
        hj.x = h[jj];
        hj.y = h[jj];
        const v2f* w2 = (const v2f*)(Wm2 + (192 + jj) * 20);
#pragma unroll
        for (int i = 0; i < 10; i++) gate2[i] += hj * w2[i];
      }
    } else {
      float g = gate2[0].x;
#pragma unroll
      for (int jj = 0; jj < 8; jj++) g += h[jj] * Wm2[192 + jj];
      gate2[0].x = g;
    }
  }
  // combine halves (both lanes execute the shfl)
#pragma unroll
  for (int i = 0; i < NP; i++) {
    v2f o;
    o.x = __shfl_xor(gate2[i].x, 1);
    o.y = __shfl_xor(gate2[i].y, 1);
    gate2[i] += o;
  }
  if (half) return;  // odd lanes done
  // x-diff tails: A fp32, B fp16-scaled; bf16 nt-stores (even lanes only)
  float invXb = ((const float*)(Br + 248))[1];
  const __half* xtb = (const __half*)(Br + 208);
  if constexpr (CIN == 20) {
    unsigned wxb[10];
    {
      uint4 s0 = *(const uint4*)(xtb);
      uint4 s1 = *(const uint4*)(xtb + 8);
      uint2 s2 = *(const uint2*)(xtb + 16);
      wxb[0] = s0.x; wxb[1] = s0.y; wxb[2] = s0.z; wxb[3] = s0.w;
      wxb[4] = s1.x; wxb[5] = s1.y; wxb[6] = s1.z; wxb[7] = s1.w;
      wxb[8] = s2.x; wxb[9] = s2.y;
    }
#pragma unroll
    for (int i = 0; i < 10; i++) {
      float2 xa = *(const float2*)(Ar + KM + 2 * i);
      float2 fb = h2f(wxb[i]);
      int c0 = 2 * i, c1 = 2 * i + 1;
      __builtin_nontemporal_store(f2bfr(gate2[i].x * (xa.x - fb.x * invXb)),
                                  gd + (size_t)c0 * E_EDGES + e);
      __builtin_nontemporal_store(f2bfr(gate2[i].y * (xa.y - fb.y * invXb)),
                                  gd + (size_t)c1 * E_EDGES + e);
    }
  } else {
    float xa = Ar[KM];
    float xb = __half2float(xtb[0]) * invXb;
    __builtin_nontemporal_store(f2bfr(gate2[0].x * (xa - xb)), gd + e);
  }
}

// Final-layer edge kernel + node-term fold (unchanged from R21 — control):
// edge part: scalar dot(gate*xd, W2), wave-segment-reduce over equal-dst runs,
// one atomicAdd per run into out[dst]. node part (threads 0..7): out[n] +=
// b1 + deg*b2 + x@W1 via atomicAdd (order-independent vs edge atomics).
__global__ void __launch_bounds__(128) edge_final_kernel(
    const int2* __restrict__ se,
    const float* __restrict__ A2, const unsigned char* __restrict__ Bq,
    const float* __restrict__ Wm2, const float* __restrict__ bm2,
    const float* __restrict__ W2,
    const int* __restrict__ off, const float* __restrict__ xrp,
    const float* __restrict__ W1, const float* __restrict__ b1,
    const float* __restrict__ b2, float* __restrict__ out) {
  int e = blockIdx.x * 128 + threadIdx.x;
  int2 sd = se[e];
  int src = sd.x;
  int dst = sd.y;
  const float* Ar = A2 + (size_t)dst * RS;
  const unsigned char* Br = Bq + (size_t)src * RSB;
  float invB = ((const float*)(Br + 248))[0];
  v2f gate2[10];
#pragma unroll
  for (int i = 0; i < 10; i++) gate2[i] = *(const v2f*)(bm2 + 2 * i);
#pragma unroll 2
  for (int k = 0; k < 192; k += 16) {
    float4 a0 = *(const float4*)(Ar + k);
    float4 a1 = *(const float4*)(Ar + k + 4);
    float4 a2 = *(const float4*)(Ar + k + 8);
    float4 a3 = *(const float4*)(Ar + k + 12);
    uint4 braw = *(const uint4*)(Br + k);
    float4 f0 = i8x4f(braw.x);
    float4 f1 = i8x4f(braw.y);
    float4 f2 = i8x4f(braw.z);
    float4 f3 = i8x4f(braw.w);
    float h[16];
    h[0] = fmaxf(a0.x + f0.x * invB, 0.f);
    h[1] = fmaxf(a0.y + f0.y * invB, 0.f);
    h[2] = fmaxf(a0.z + f0.z * invB, 0.f);
    h[3] = fmaxf(a0.w + f0.w * invB, 0.f);
    h[4] = fmaxf(a1.x + f1.x * invB, 0.f);
    h[5] = fmaxf(a1.y + f1.y * invB, 0.f);
    h[6] = fmaxf(a1.z + f1.z * invB, 0.f);
    h[7] = fmaxf(a1.w + f1.w * invB, 0.f);
    h[8] = fmaxf(a2.x + f2.x * invB, 0.f);
    h[9] = fmaxf(a2.y + f2.y * invB, 0.f);
    h[10] = fmaxf(a2.z + f2.z * invB, 0.f);
    h[11] = fmaxf(a2.w + f2.w * invB, 0.f);
    h[12] = fmaxf(a3.x + f3.x * invB, 0.f);
    h[13] = fmaxf(a3.y + f3.y * invB, 0.f);
    h[14] = fmaxf(a3.z + f3.z * invB, 0.f);
    h[15] = fmaxf(a3.w + f3.w * invB, 0.f);
#pragma unroll
    for (int j = 0; j < 16; j++) {
      v2f hj;
      hj.x = h[j];
      hj.y = h[j];
      const v2f* w2 = (const v2f*)(Wm2 + (k + j) * 20);
#pragma unroll
      for (int i = 0; i < 10; i++) gate2[i] += hj * w2[i];
    }
  }
  {  // tail k = 192..199
    float4 a0 = *(const float4*)(Ar + 192);
    float4 a1 = *(const float4*)(Ar + 196);
    uint2 braw = *(const uint2*)(Br + 192);
    float4 f01 = i8x4f(braw.x);
    float4 f23 = i8x4f(braw.y);
    float h[8];
    h[0] = fmaxf(a0.x + f01.x * invB, 0.f);
    h[1] = fmaxf(a0.y + f01.y * invB, 0.f);
    h[2] = fmaxf(a0.z + f01.z * invB, 0.f);
    h[3] = fmaxf(a0.w + f01.w * invB, 0.f);
    h[4] = fmaxf(a1.x + f23.x * invB, 0.f);
    h[5] = fmaxf(a1.y + f23.y * invB, 0.f);
    h[6] = fmaxf(a1.z + f23.z * invB, 0.f);
    h[7] = fmaxf(a1.w + f23.w * invB, 0.f);
#pragma unroll
    for (int j = 0; j < 8; j++) {
      v2f hj;
      hj.x = h[j];
      hj.y = h[j];
      const v2f* w2 = (const v2f*)(Wm2 + (192 + j) * 20);
#pragma unroll
      for (int i = 0; i < 10; i++) gate2[i] += hj * w2[i];
    }
  }
  // scalar edge contribution: dot(gate * xd, W2)
  float invXb = ((const float*)(Br + 248))[1];
  const __half* xtb = (const __half*)(Br + 208);
  unsigned wxb[10];
  {
    uint4 s0 = *(const uint4*)(xtb);
    uint4 s1 = *(const uint4*)(xtb + 8);
    uint2 s2 = *(const uint2*)(xtb + 16);
    wxb[0] = s0.x; wxb[1] = s0.y; wxb[2] = s0.z; wxb[3] = s0.w;
    wxb[4] = s1.x; wxb[5] = s1.y; wxb[6] = s1.z; wxb[7] = s1.w;
    wxb[8] = s2.x; wxb[9] = s2.y;
  }
  float sv = 0.f;
#pragma unroll
  for (int i = 0; i < 10; i++) {
    float2 xa = *(const float2*)(Ar + KM + 2 * i);
    float2 fb = h2f(wxb[i]);
    sv += gate2[i].x * (xa.x - fb.x * invXb) * W2[2 * i] +
          gate2[i].y * (xa.y - fb.y * invXb) * W2[2 * i + 1];
  }
  // wave-level segmented sum over equal-dst runs (dst-sorted), then 1 atomic/run
  int lane = threadIdx.x & 63;
  bool seg[6];
#pragma unroll
  for (int i = 0; i < 6; i++) {
    int s = 1 << i;
    int od = __shfl_up(dst, s);
    seg[i] = (lane >= s) && (od == dst);
  }
#pragma unroll
  for (int i = 0; i < 6; i++) {
    float o = __shfl_up(sv, 1 << i);
    if (seg[i]) sv += o;
  }
  int dn = __shfl_down(dst, 1);
  bool is_last = (lane == 63) || (dn != dst);
  if (is_last) atomicAdd(out + dst, sv);
  // node-term fold: 8 nodes/block, grid 3125 = N/8
  int tid = threadIdx.x;
  if (tid < 8) {
    int n = blockIdx.x * 8 + tid;
    float deg = (float)(off[n + 1] - off[n]);
    float v = b1[0] + deg * b2[0];
    const float* xp = xrp + (size_t)n * 20;
#pragma unroll
    for (int c = 0; c < 20; c++) v += xp[c] * W1[c];
    atomicAdd(out + n, v);
  }
}

// afp1: after layer-d edge (gd 1-channel bf16). Per block: 8 nodes.
__global__ void __launch_bounds__(256) afp1_kernel(
    const unsigned short* __restrict__ gd, const int* __restrict__ off,
    const float* __restrict__ xrp,
    const float* __restrict__ W1, const float* __restrict__ b1,
    const float* __restrict__ W2, const float* __restrict__ b2,
    const float* __restrict__ Wm1n, const float* __restrict__ bm1n,
    float* __restrict__ A2, unsigned char* __restrict__ Bq, float* __restrict__ xrn) {
  __shared__ float ag[8], xp[8], degs[8];
  __shared__ float xv[8][21];
  __shared__ unsigned bmaxu[8];
  __shared__ float xmaxs[8];
  int tid = threadIdx.x;
  int n0 = blockIdx.x * 8;
  if (tid < 8) {
    bmaxu[tid] = 0;
    int n = n0 + tid;
    int s = off[n], t = off[n + 1];
    ag[tid] = seg_sum_bf16(gd, s, t);
    xp[tid] = xrp[n];
    degs[tid] = (float)(t - s);
  }
  __syncthreads();
  if (tid < 160) {
    int o = tid >> 3, nl = tid & 7;
    float v = b1[o] + degs[nl] * b2[o] + ag[nl] * W2[o] + xp[nl] * W1[o];
    float r = fmaxf(v, 0.f);
    xv[nl][o] = r;
    xrn[(n0 + nl) * 20 + o] = r;
  }
  __syncthreads();
  if (tid < 8) {
    float m = 0.f;
#pragma unroll
    for (int c = 0; c < 20; c++) m = fmaxf(m, xv[tid][c]);
    xmaxs[tid] = fmaxf(m, 1e-30f);
  }
  int k = tid;
  float aa[8], bb[8];
  if (k < KM) {
    v2f wab[20];
    float bm = bm1n[k];
#pragma unroll
    for (int c = 0; c < 20; c++) {
      wab[c].x = Wm1n[c * KM + k];
      wab[c].y = Wm1n[(20 + c) * KM + k];
    }
#pragma unroll
    for (int nl = 0; nl < 8; nl++) {
      v2f acc;
      acc.x = bm;
      acc.y = 0.f;
#pragma unroll
      for (int c = 0; c < 20; c++) {
        v2f xc;
        xc.x = xv[nl][c];
        xc.y = xv[nl][c];
        acc += xc * wab[c];
      }
      aa[nl] = acc.x;
      bb[nl] = acc.y;
    }
  }
  float mxb[8];
#pragma unroll
  for (int nl = 0; nl < 8; nl++) mxb[nl] = (k < KM) ? fabsf(bb[nl]) : 0.f;
#pragma unroll
  for (int s = 1; s < 64; s <<= 1) {
#pragma unroll
    for (int nl = 0; nl < 8; nl++) mxb[nl] = fmaxf(mxb[nl], __shfl_xor(mxb[nl], s));
  }
  if ((tid & 63) == 0) {
#pragma unroll
    for (int nl = 0; nl < 8; nl++) atomicMax(&bmaxu[nl], __float_as_uint(mxb[nl]));
  }
  __syncthreads();
  if (k < KM) {
#pragma unroll
    for (int nl = 0; nl < 8; nl++) {
      float bmax = fmaxf(__uint_as_float(bmaxu[nl]), 1e-30f);
      float xmax = xmaxs[nl];
      size_t rowA = (size_t)(n0 + nl) * RS;
      unsigned char* rb = Bq + (size_t)(n0 + nl) * RSB;
      A2[rowA + k] = aa[nl];
      rb[k] = (unsigned char)(signed char)lrintf(bb[nl] * (127.f / bmax));
      if (k < 20) {
        A2[rowA + KM + k] = xv[nl][k];
        ((__half*)(rb + 208))[k] = __float2half(xv[nl][k] * (32768.f / xmax));
      }
      if (k == 0) {
        ((float*)(rb + 248))[0] = bmax / 127.f;
        ((float*)(rb + 248))[1] = xmax / 32768.f;
      }
    }
  }
}

// afp20: after a hidden edge (gd 20-channel bf16). Same 3 phases, CIN=20.
__global__ void __launch_bounds__(256) afp20_kernel(
    const unsigned short* __restrict__ gd, const int* __restrict__ off,
    const float* __restrict__ xrp,
    const float* __restrict__ W1, const float* __restrict__ b1,
    const float* __restrict__ W2, const float* __restrict__ b2,
    const float* __restrict__ Wm1n, const float* __restrict__ bm1n,
    float* __restrict__ A2, unsigned char* __restrict__ Bq, float* __restrict__ xrn) {
  __shared__ float ag[8][21], xp[8][21], xv[8][21], degs[8];
  __shared__ unsigned bmaxu[8];
  __shared__ float xmaxs[8];
  int tid = threadIdx.x;
  int n0 = blockIdx.x * 8;
  if (tid < 8) bmaxu[tid] = 0;
  if (tid < 160) {
    int c = tid >> 3, nl = tid & 7;  // adjacent lanes: same c, adjacent n
    int n = n0 + nl;
    int s = off[n], t = off[n + 1];
    ag[nl][c] = seg_sum_bf16(gd + (size_t)c * E_EDGES, s, t);
    xp[nl][c] = xrp[n * 20 + c];
    if (c == 0) degs[nl] = (float)(t - s);
  }
  __syncthreads();
  if (tid < 160) {
    int o = tid >> 3, nl = tid & 7;
    float v = b1[o] + degs[nl] * b2[o];
#pragma unroll
    for (int c = 0; c < 20; c++) {
      v += ag[nl][c] * W2[c * 20 + o] + xp[nl][c] * W1[c * 20 + o];
    }
    float r = fmaxf(v, 0.f);
    xv[nl][o] = r;
    xrn[(n0 + nl) * 20 + o] = r;
  }
  __syncthreads();
  if (tid < 8) {
    float m = 0.f;
#pragma unroll
    for (int c = 0; c < 20; c++) m = fmaxf(m, xv[tid][c]);
    xmaxs[tid] = fmaxf(m, 1e-30f);
  }
  int k = tid;
  float aa[8], bb[8];
  if (k < KM) {
    v2f wab[20];
    float bm = bm1n[k];
#pragma unroll
    for (int c = 0; c < 20; c++) {
      wab[c].x = Wm1n[c * KM + k];
      wab[c].y = Wm1n[(20 + c) * KM + k];
    }
#pragma unroll
    for (int nl = 0; nl < 8; nl++) {
      v2f acc;
      acc.x = bm;
      acc.y = 0.f;
#pragma unroll
      for (int c = 0; c < 20; c++) {
        v2f xc;
        xc.x = xv[nl][c];
        xc.y = xv[nl][c];
        acc += xc * wab[c];
      }
      aa[nl] = acc.x;
      bb[nl] = acc.y;
    }
  }
  float mxb[8];
#pragma unroll
  for (int nl = 0; nl < 8; nl++) mxb[nl] = (k < KM) ? fabsf(bb[nl]) : 0.f;
#pragma unroll
  for (int s = 1; s < 64; s <<= 1) {
#pragma unroll
    for (int nl = 0; nl < 8; nl++) mxb[nl] = fmaxf(mxb[nl], __shfl_xor(mxb[nl], s));
  }
  if ((tid & 63) == 0) {
#pragma unroll
    for (int nl = 0; nl < 8; nl++) atomicMax(&bmaxu[nl], __float_as_uint(mxb[nl]));
  }
  __syncthreads();
  if (k < KM) {
#pragma unroll
    for (int nl = 0; nl < 8; nl++) {
      float bmax = fmaxf(__uint_as_float(bmaxu[nl]), 1e-30f);
      float xmax = xmaxs[nl];
      size_t rowA = (size_t)(n0 + nl) * RS;
      unsigned char* rb = Bq + (size_t)(n0 + nl) * RSB;
      A2[rowA + k] = aa[nl];
      rb[k] = (unsigned char)(signed char)lrintf(bb[nl] * (127.f / bmax));
      if (k < 20) {
        A2[rowA + KM + k] = xv[nl][k];
        ((__half*)(rb + 208))[k] = __float2half(xv[nl][k] * (32768.f / xmax));
      }
      if (k == 0) {
        ((float*)(rb + 248))[0] = bmax / 127.f;
        ((float*)(rb + 248))[1] = xmax / 32768.f;
      }
    }
  }
}

// ---------------- launch ----------------

extern "C" void kernel_launch(void* const* d_in, const int* in_sizes, int n_in,
                              void* d_out, int out_size, void* d_ws, size_t ws_size,
                              hipStream_t stream) {
  const float* features = (const float*)d_in[0];
  const int* edges = (const int*)d_in[1];
  // d_in[2] = weights (unused by reference)

  const float *dW1 = (const float*)d_in[3], *db1 = (const float*)d_in[4],
              *dWm1 = (const float*)d_in[5], *dbm1 = (const float*)d_in[6],
              *dWm2 = (const float*)d_in[7], *dbm2 = (const float*)d_in[8],
              *dW2 = (const float*)d_in[9], *db2 = (const float*)d_in[10];
  const float *hW1 = (const float*)d_in[11], *hb1 = (const float*)d_in[12],
              *hWm1 = (const float*)d_in[13], *hbm1 = (const float*)d_in[14],
              *hWm2 = (const float*)d_in[15], *hbm2 = (const float*)d_in[16],
              *hW2 = (const float*)d_in[17], *hb2 = (const float*)d_in[18];
  const float *oW1 = (const float*)d_in[19], *ob1 = (const float*)d_in[20],
              *oWm1 = (const float*)d_in[21], *obm1 = (const float*)d_in[22],
              *oWm2 = (const float*)d_in[23], *obm2 = (const float*)d_in[24],
              *oW2 = (const float*)d_in[25], *ob2 = (const float*)d_in[26];

  // workspace layout (float units)
  float* fws = (float*)d_ws;
  size_t o = 0;
  float* A2 = fws + o;                           o += (size_t)N_NODES * RS;       // 5.6M
  unsigned char* Bq = (unsigned char*)(fws + o); o += (size_t)N_NODES * RSB / 4;  // 1.6M floats
  unsigned short* gd = (unsigned short*)(fws + o); o += (size_t)20 * E_EDGES / 2; // 4.0M floats (bf16)
  float* xrA = fws + o;                          o += (size_t)N_NODES * 20;
  float* xrB = fws + o;                          o += (size_t)N_NODES * 20;
  int* ip = (int*)(fws + o);
  int* hist = ip;   ip += N_NODES;
  int* off = ip;    ip += N_NODES + 4;
  int* cursor = ip; ip += N_NODES;
  int2* se = (int2*)ip;

  const int B256 = 256;
  const int EDGE_G = E_EDGES / 64;    // 6250, exact (2 threads/edge, 128-thread blocks)
  const int EDGEF_G = E_EDGES / 128;  // 3125, exact (edge_final: 1 thread/edge)
  const int NODE8_G = N_NODES / 8;    // 3125, exact

  // build dst-sorted edge list + CSR offsets (recomputed every launch)
  (void)hipMemsetAsync(hist, 0, N_NODES * sizeof(int), stream);
  hist_kernel<<<(E_EDGES + B256 - 1) / B256, B256, 0, stream>>>(edges, hist);
  scan_kernel<<<1, 1024, 0, stream>>>(hist, off, cursor);

  // layer d: 1 -> 20 (scatter + d_out zeroing fused into prep)
  scatter_prep_d_kernel<<<NODE8_G, B256, 0, stream>>>(edges, cursor, se, features,
                                                      dWm1, dbm1, A2, Bq, xrA,
                                                      (float*)d_out);
  edge_kernel<1><<<EDGE_G, 128, 0, stream>>>(se, A2, Bq, dWm2, dbm2, gd);
  afp1_kernel<<<NODE8_G, B256, 0, stream>>>(gd, off, xrA, dW1, db1, dW2, db2,
                                            hWm1, hbm1, A2, Bq, xrB);

  // hidden1
  edge_kernel<20><<<EDGE_G, 128, 0, stream>>>(se, A2, Bq, hWm2, hbm2, gd);
  afp20_kernel<<<NODE8_G, B256, 0, stream>>>(gd, off, xrB, hW1, hb1, hW2, hb2,
                                             hWm1, hbm1, A2, Bq, xrA);
  // hidden2
  edge_kernel<20><<<EDGE_G, 128, 0, stream>>>(se, A2, Bq, hWm2, hbm2, gd);
  afp20_kernel<<<NODE8_G, B256, 0, stream>>>(gd, off, xrA, hW1, hb1, hW2, hb2,
                                             hWm1, hbm1, A2, Bq, xrB);
  // hidden3 -> preps output layer (oWm1)
  edge_kernel<20><<<EDGE_G, 128, 0, stream>>>(se, A2, Bq, hWm2, hbm2, gd);
  afp20_kernel<<<NODE8_G, B256, 0, stream>>>(gd, off, xrB, hW1, hb1, hW2, hb2,
                                             oWm1, obm1, A2, Bq, xrA);
  // output layer: 20 -> 1, gd-free (scalar atomics into d_out) + node terms fused
  edge_final_kernel<<<EDGEF_G, 128, 0, stream>>>(se, A2, Bq, oWm2, obm2, oW2,
                                                 off, xrA, oW1, ob1, ob2,
                                                 (float*)d_out);
}

// Round 23
// 557.426 us; speedup vs baseline: 2.6772x; 2.6772x over previous
//
#include <hip/hip_runtime.h>
#include <hip/hip_fp16.h>

#define N_NODES 25000   // = 3125 * 8 exactly
#define E_EDGES 400000
#define KM 200      // message channels
#define RS 224      // A-row stride (floats): 200 fp32 A | 20 fp32 x | pad (896 B)
#define RSB 256     // B-row stride BYTES: 200 int8 | pad | 20 fp16 x @208 | inv_p,inv_x @248

typedef float v2f __attribute__((ext_vector_type(2)));  // v_pk_fma_f32 operand

__device__ __forceinline__ float2 h2f(unsigned u) {
  return __half22float2(*(const __half2*)&u);
}
__device__ __forceinline__ float4 i8x4f(unsigned u) {
  float4 f;
  f.x = (float)((int)(u << 24) >> 24);
  f.y = (float)((int)(u << 16) >> 24);
  f.z = (float)((int)(u << 8) >> 24);
  f.w = (float)((int)u >> 24);
  return f;
}
// bf16 round-half-up pack / unpack (gd is bf16 to halve its HBM round-trip)
__device__ __forceinline__ unsigned short f2bfr(float v) {
  unsigned u = __float_as_uint(v) + 0x8000u;
  return (unsigned short)(u >> 16);
}
__device__ __forceinline__ float bf2f(unsigned short h) {
  return __uint_as_float((unsigned)h << 16);
}

// Segment sum with batched loads: 8 loads in flight, adds in original order
// (single accumulator, sequential) -> bitwise-identical to the naive loop.
__device__ __forceinline__ float seg_sum_bf16(const unsigned short* __restrict__ g,
                                              int s, int t) {
  float v = 0.f;
  int e = s;
  int t8 = s + ((t - s) & ~7);
  for (; e < t8; e += 8) {
    unsigned short u0 = g[e + 0], u1 = g[e + 1], u2 = g[e + 2], u3 = g[e + 3];
    unsigned short u4 = g[e + 4], u5 = g[e + 5], u6 = g[e + 6], u7 = g[e + 7];
    v += bf2f(u0); v += bf2f(u1); v += bf2f(u2); v += bf2f(u3);
    v += bf2f(u4); v += bf2f(u5); v += bf2f(u6); v += bf2f(u7);
  }
  int t2 = s + ((t - s) & ~1);
  for (; e < t2; e += 2) {
    unsigned short u0 = g[e + 0], u1 = g[e + 1];
    v += bf2f(u0); v += bf2f(u1);
  }
  if (e < t) v += bf2f(g[e]);
  return v;
}

// ---------------- sort-by-dst (CSR build) ----------------

__global__ void hist_kernel(const int* __restrict__ edges, int* __restrict__ hist) {
  int e = blockIdx.x * blockDim.x + threadIdx.x;
  if (e < E_EDGES) atomicAdd(&hist[edges[E_EDGES + e]], 1);
}

__global__ void scan_kernel(const int* __restrict__ hist, int* __restrict__ off,
                            int* __restrict__ cursor) {
  __shared__ int sums[1024];
  const int CH = (N_NODES + 1023) / 1024;  // 25
  int tid = threadIdx.x;
  int base = tid * CH;
  int s = 0;
  for (int i = 0; i < CH; i++) {
    int idx = base + i;
    if (idx < N_NODES) s += hist[idx];
  }
  sums[tid] = s;
  __syncthreads();
  for (int d = 1; d < 1024; d <<= 1) {
    int v = (tid >= d) ? sums[tid - d] : 0;
    __syncthreads();
    sums[tid] += v;
    __syncthreads();
  }
  int run = (tid == 0) ? 0 : sums[tid - 1];
  for (int i = 0; i < CH; i++) {
    int idx = base + i;
    if (idx < N_NODES) {
      off[idx] = run;
      cursor[idx] = run;
      run += hist[idx];
    }
  }
  if (tid == 1023) off[N_NODES] = run;  // == E
}

// ---------------- per-layer kernels ----------------

// Fused: scatter (128 edges/block) + prep layer-d (8 nodes/block) + d_out zeroing.
// prep: A fp32; B int8 (exact bound: max_k |x*wb_k| = |x|*wbmax); x-tail fp16.
__global__ void __launch_bounds__(256) scatter_prep_d_kernel(
    const int* __restrict__ edges, int* __restrict__ cursor, int2* __restrict__ se,
    const float* __restrict__ xin,
    const float* __restrict__ Wm1, const float* __restrict__ bm1,
    float* __restrict__ A2, unsigned char* __restrict__ Bq, float* __restrict__ xr,
    float* __restrict__ out) {
  int tid = threadIdx.x;
  // d_out zeroing (edge_final accumulates atomically): 3125 * 8 = 25000 exactly
  if (tid < 8) out[blockIdx.x * 8 + tid] = 0.f;
  // scatter part: 3125 * 128 = 400000 exactly
  if (tid < 128) {
    int e = blockIdx.x * 128 + tid;
    int s = edges[e];
    int d = edges[E_EDGES + e];
    int pos = atomicAdd(&cursor[d], 1);
    se[pos] = make_int2(s, d);
  }
  // prep part
  __shared__ unsigned wbmaxu;
  if (tid == 0) wbmaxu = 0;
  __syncthreads();
  int k = tid;
  float wa = 0.f, wb = 0.f, bm = 0.f;
  if (k < KM) {
    bm = bm1[k];
    wa = Wm1[k];
    wb = Wm1[KM + k];
  }
  float mb = (k < KM) ? fabsf(wb) : 0.f;
#pragma unroll
  for (int s = 1; s < 64; s <<= 1) mb = fmaxf(mb, __shfl_xor(mb, s));
  if ((k & 63) == 0) atomicMax(&wbmaxu, __float_as_uint(mb));
  __syncthreads();
  float wbmax = fmaxf(__uint_as_float(wbmaxu), 1e-30f);
  int n0 = blockIdx.x * 8;
  for (int i = 0; i < 8; i++) {
    int n = n0 + i;
    float xv = xin[n];
    float bBound = fmaxf(fabsf(xv) * wbmax, 1e-30f);
    float xBound = fmaxf(fabsf(xv), 1e-30f);
    size_t rowA = (size_t)n * RS;
    unsigned char* rb = Bq + (size_t)n * RSB;
    if (k == 0) {
      xr[n] = xv;
      A2[rowA + KM] = xv;
      ((__half*)(rb + 208))[0] = __float2half(xv * (32768.f / xBound));
      ((float*)(rb + 248))[0] = bBound / 127.f;
      ((float*)(rb + 248))[1] = xBound / 32768.f;
    }
    if (k < KM) {
      A2[rowA + k] = bm + xv * wa;
      rb[k] = (unsigned char)(signed char)lrintf(xv * wb * (127.f / bBound));
    }
  }
}

// Edge kernel (R18 shape — measured optimum): one thread per (dst-sorted) edge,
// 128-thread blocks. A fp32 (dst-shared, streamed), B int8 256 B gathered
// line-by-line. k is wave-uniform -> Wm2 reads compile to scalar loads (free).
// h_k = relu(A[dst][k] + B8[src][k]*invB); gate = h@Wm2 + bm2 via v_pk_fma_f32;
// gd [c][e] bf16 nt-stores.
template <int CIN>
__global__ void __launch_bounds__(128) edge_kernel(
    const int2* __restrict__ se,
    const float* __restrict__ A2, const unsigned char* __restrict__ Bq,
    const float* __restrict__ Wm2, const float* __restrict__ bm2,
    unsigned short* __restrict__ gd) {
  int e = blockIdx.x * 128 + threadIdx.x;  // grid exact: no bounds check
  int2 sd = se[e];
  int src = sd.x;
  int dst = sd.y;
  const float* Ar = A2 + (size_t)dst * RS;
  const unsigned char* Br = Bq + (size_t)src * RSB;
  float invB = ((const float*)(Br + 248))[0];
  constexpr int NP = (CIN + 1) / 2;
  v2f gate2[NP];
  if constexpr (CIN == 20) {
#pragma unroll
    for (int i = 0; i < NP; i++) gate2[i] = *(const v2f*)(bm2 + 2 * i);
  } else {
    gate2[0].x = bm2[0];
    gate2[0].y = 0.f;
  }
#pragma unroll 2
  for (int k = 0; k < 192; k += 16) {
    float4 a0 = *(const float4*)(Ar + k);
    float4 a1 = *(const float4*)(Ar + k + 4);
    float4 a2 = *(const float4*)(Ar + k + 8);
    float4 a3 = *(const float4*)(Ar + k + 12);
    uint4 braw = *(const uint4*)(Br + k);  // 16 int8
    float4 f0 = i8x4f(braw.x);
    float4 f1 = i8x4f(braw.y);
    float4 f2 = i8x4f(braw.z);
    float4 f3 = i8x4f(braw.w);
    float h[16];
    h[0] = fmaxf(a0.x + f0.x * invB, 0.f);
    h[1] = fmaxf(a0.y + f0.y * invB, 0.f);
    h[2] = fmaxf(a0.z + f0.z * invB, 0.f);
    h[3] = fmaxf(a0.w + f0.w * invB, 0.f);
    h[4] = fmaxf(a1.x + f1.x * invB, 0.f);
    h[5] = fmaxf(a1.y + f1.y * invB, 0.f);
    h[6] = fmaxf(a1.z + f1.z * invB, 0.f);
    h[7] = fmaxf(a1.w + f1.w * invB, 0.f);
    h[8] = fmaxf(a2.x + f2.x * invB, 0.f);
    h[9] = fmaxf(a2.y + f2.y * invB, 0.f);
    h[10] = fmaxf(a2.z + f2.z * invB, 0.f);
    h[11] = fmaxf(a2.w + f2.w * invB, 0.f);
    h[12] = fmaxf(a3.x + f3.x * invB, 0.f);
    h[13] = fmaxf(a3.y + f3.y * invB, 0.f);
    h[14] = fmaxf(a3.z + f3.z * invB, 0.f);
    h[15] = fmaxf(a3.w + f3.w * invB, 0.f);
    if constexpr (CIN == 20) {
#pragma unroll
      for (int j = 0; j < 16; j++) {
        v2f hj;
        hj.x = h[j];
        hj.y = h[j];
        const v2f* w2 = (const v2f*)(Wm2 + (k + j) * 20);
#pragma unroll
        for (int i = 0; i < 10; i++) gate2[i] += hj * w2[i];
      }
    } else {
      float g = gate2[0].x;
#pragma unroll
      for (int j = 0; j < 16; j++) g += h[j] * Wm2[k + j];
      gate2[0].x = g;
    }
  }
  {  // tail k = 192..199
    float4 a0 = *(const float4*)(Ar + 192);
    float4 a1 = *(const float4*)(Ar + 196);
    uint2 braw = *(const uint2*)(Br + 192);
    float4 f01 = i8x4f(braw.x);
    float4 f23 = i8x4f(braw.y);
    float h[8];
    h[0] = fmaxf(a0.x + f01.x * invB, 0.f);
    h[1] = fmaxf(a0.y + f01.y * invB, 0.f);
    h[2] = fmaxf(a0.z + f01.z * invB, 0.f);
    h[3] = fmaxf(a0.w + f01.w * invB, 0.f);
    h[4] = fmaxf(a1.x + f23.x * invB, 0.f);
    h[5] = fmaxf(a1.y + f23.y * invB, 0.f);
    h[6] = fmaxf(a1.z + f23.z * invB, 0.f);
    h[7] = fmaxf(a1.w + f23.w * invB, 0.f);
    if constexpr (CIN == 20) {
#pragma unroll
      for (int j = 0; j < 8; j++) {
        v2f hj;
        hj.x = h[j];
        hj.y = h[j];
        const v2f* w2 = (const v2f*)(Wm2 + (192 + j) * 20);
#pragma unroll
        for (int i = 0; i < 10; i++) gate2[i] += hj * w2[i];
      }
    } else {
      float g = gate2[0].x;
#pragma unroll
      for (int j = 0; j < 8; j++) g += h[j] * Wm2[192 + j];
      gate2[0].x = g;
    }
  }
  // x-diff tails: A fp32, B fp16-scaled; coalesced nontemporal bf16 stores
  float invXb = ((const float*)(Br + 248))[1];
  const __half* xtb = (const __half*)(Br + 208);
  if constexpr (CIN == 20) {
    unsigned wxb[10];
    {
      uint4 s0 = *(const uint4*)(xtb);
      uint4 s1 = *(const uint4*)(xtb + 8);
      uint2 s2 = *(const uint2*)(xtb + 16);
      wxb[0] = s0.x; wxb[1] = s0.y; wxb[2] = s0.z; wxb[3] = s0.w;
      wxb[4] = s1.x; wxb[5] = s1.y; wxb[6] = s1.z; wxb[7] = s1.w;
      wxb[8] = s2.x; wxb[9] = s2.y;
    }
#pragma unroll
    for (int i = 0; i < 10; i++) {
      float2 xa = *(const float2*)(Ar + KM + 2 * i);
      float2 fb = h2f(wxb[i]);
      int c0 = 2 * i, c1 = 2 * i + 1;
      __builtin_nontemporal_store(f2bfr(gate2[i].x * (xa.x - fb.x * invXb)),
                                  gd + (size_t)c0 * E_EDGES + e);
      __builtin_nontemporal_store(f2bfr(gate2[i].y * (xa.y - fb.y * invXb)),
                                  gd + (size_t)c1 * E_EDGES + e);
    }
  } else {
    float xa = Ar[KM];
    float xb = __half2float(xtb[0]) * invXb;
    __builtin_nontemporal_store(f2bfr(gate2[0].x * (xa - xb)), gd + e);
  }
}

// Final-layer edge kernel + node-term fold:
// edge part: scalar dot(gate*xd, W2), wave-segment-reduce over equal-dst runs,
// one atomicAdd per run into out[dst]. node part (threads 0..7): out[n] +=
// b1 + deg*b2 + x@W1 via atomicAdd (order-independent vs edge atomics).
__global__ void __launch_bounds__(128) edge_final_kernel(
    const int2* __restrict__ se,
    const float* __restrict__ A2, const unsigned char* __restrict__ Bq,
    const float* __restrict__ Wm2, const float* __restrict__ bm2,
    const float* __restrict__ W2,
    const int* __restrict__ off, const float* __restrict__ xrp,
    const float* __restrict__ W1, const float* __restrict__ b1,
    const float* __restrict__ b2, float* __restrict__ out) {
  int e = blockIdx.x * 128 + threadIdx.x;
  int2 sd = se[e];
  int src = sd.x;
  int dst = sd.y;
  const float* Ar = A2 + (size_t)dst * RS;
  const unsigned char* Br = Bq + (size_t)src * RSB;
  float invB = ((const float*)(Br + 248))[0];
  v2f gate2[10];
#pragma unroll
  for (int i = 0; i < 10; i++) gate2[i] = *(const v2f*)(bm2 + 2 * i);
#pragma unroll 2
  for (int k = 0; k < 192; k += 16) {
    float4 a0 = *(const float4*)(Ar + k);
    float4 a1 = *(const float4*)(Ar + k + 4);
    float4 a2 = *(const float4*)(Ar + k + 8);
    float4 a3 = *(const float4*)(Ar + k + 12);
    uint4 braw = *(const uint4*)(Br + k);
    float4 f0 = i8x4f(braw.x);
    float4 f1 = i8x4f(braw.y);
    float4 f2 = i8x4f(braw.z);
    float4 f3 = i8x4f(braw.w);
    float h[16];
    h[0] = fmaxf(a0.x + f0.x * invB, 0.f);
    h[1] = fmaxf(a0.y + f0.y * invB, 0.f);
    h[2] = fmaxf(a0.z + f0.z * invB, 0.f);
    h[3] = fmaxf(a0.w + f0.w * invB, 0.f);
    h[4] = fmaxf(a1.x + f1.x * invB, 0.f);
    h[5] = fmaxf(a1.y + f1.y * invB, 0.f);
    h[6] = fmaxf(a1.z + f1.z * invB, 0.f);
    h[7] = fmaxf(a1.w + f1.w * invB, 0.f);
    h[8] = fmaxf(a2.x + f2.x * invB, 0.f);
    h[9] = fmaxf(a2.y + f2.y * invB, 0.f);
    h[10] = fmaxf(a2.z + f2.z * invB, 0.f);
    h[11] = fmaxf(a2.w + f2.w * invB, 0.f);
    h[12] = fmaxf(a3.x + f3.x * invB, 0.f);
    h[13] = fmaxf(a3.y + f3.y * invB, 0.f);
    h[14] = fmaxf(a3.z + f3.z * invB, 0.f);
    h[15] = fmaxf(a3.w + f3.w * invB, 0.f);
#pragma unroll
    for (int j = 0; j < 16; j++) {
      v2f hj;
      hj.x = h[j];
      hj.y = h[j];
      const v2f* w2 = (const v2f*)(Wm2 + (k + j) * 20);
#pragma unroll
      for (int i = 0; i < 10; i++) gate2[i] += hj * w2[i];
    }
  }
  {  // tail k = 192..199
    float4 a0 = *(const float4*)(Ar + 192);
    float4 a1 = *(const float4*)(Ar + 196);
    uint2 braw = *(const uint2*)(Br + 192);
    float4 f01 = i8x4f(braw.x);
    float4 f23 = i8x4f(braw.y);
    float h[8];
    h[0] = fmaxf(a0.x + f01.x * invB, 0.f);
    h[1] = fmaxf(a0.y + f01.y * invB, 0.f);
    h[2] = fmaxf(a0.z + f01.z * invB, 0.f);
    h[3] = fmaxf(a0.w + f01.w * invB, 0.f);
    h[4] = fmaxf(a1.x + f23.x * invB, 0.f);
    h[5] = fmaxf(a1.y + f23.y * invB, 0.f);
    h[6] = fmaxf(a1.z + f23.z * invB, 0.f);
    h[7] = fmaxf(a1.w + f23.w * invB, 0.f);
#pragma unroll
    for (int j = 0; j < 8; j++) {
      v2f hj;
      hj.x = h[j];
      hj.y = h[j];
      const v2f* w2 = (const v2f*)(Wm2 + (192 + j) * 20);
#pragma unroll
      for (int i = 0; i < 10; i++) gate2[i] += hj * w2[i];
    }
  }
  // scalar edge contribution: dot(gate * xd, W2)
  float invXb = ((const float*)(Br + 248))[1];
  const __half* xtb = (const __half*)(Br + 208);
  unsigned wxb[10];
  {
    uint4 s0 = *(const uint4*)(xtb);
    uint4 s1 = *(const uint4*)(xtb + 8);
    uint2 s2 = *(const uint2*)(xtb + 16);
    wxb[0] = s0.x; wxb[1] = s0.y; wxb[2] = s0.z; wxb[3] = s0.w;
    wxb[4] = s1.x; wxb[5] = s1.y; wxb[6] = s1.z; wxb[7] = s1.w;
    wxb[8] = s2.x; wxb[9] = s2.y;
  }
  float sv = 0.f;
#pragma unroll
  for (int i = 0; i < 10; i++) {
    float2 xa = *(const float2*)(Ar + KM + 2 * i);
    float2 fb = h2f(wxb[i]);
    sv += gate2[i].x * (xa.x - fb.x * invXb) * W2[2 * i] +
          gate2[i].y * (xa.y - fb.y * invXb) * W2[2 * i + 1];
  }
  // wave-level segmented sum over equal-dst runs (dst-sorted), then 1 atomic/run
  int lane = threadIdx.x & 63;
  bool seg[6];
#pragma unroll
  for (int i = 0; i < 6; i++) {
    int s = 1 << i;
    int od = __shfl_up(dst, s);
    seg[i] = (lane >= s) && (od == dst);
  }
#pragma unroll
  for (int i = 0; i < 6; i++) {
    float o = __shfl_up(sv, 1 << i);
    if (seg[i]) sv += o;
  }
  int dn = __shfl_down(dst, 1);
  bool is_last = (lane == 63) || (dn != dst);
  if (is_last) atomicAdd(out + dst, sv);
  // node-term fold: 8 nodes/block, grid 3125 = N/8
  int tid = threadIdx.x;
  if (tid < 8) {
    int n = blockIdx.x * 8 + tid;
    float deg = (float)(off[n + 1] - off[n]);
    float v = b1[0] + deg * b2[0];
    const float* xp = xrp + (size_t)n * 20;
#pragma unroll
    for (int c = 0; c < 20; c++) v += xp[c] * W1[c];
    atomicAdd(out + n, v);
  }
}

// afp1: after layer-d edge (gd 1-channel bf16). Per block: 8 nodes.
__global__ void __launch_bounds__(256) afp1_kernel(
    const unsigned short* __restrict__ gd, const int* __restrict__ off,
    const float* __restrict__ xrp,
    const float* __restrict__ W1, const float* __restrict__ b1,
    const float* __restrict__ W2, const float* __restrict__ b2,
    const float* __restrict__ Wm1n, const float* __restrict__ bm1n,
    float* __restrict__ A2, unsigned char* __restrict__ Bq, float* __restrict__ xrn) {
  __shared__ float ag[8], xp[8], degs[8];
  __shared__ float xv[8][21];
  __shared__ unsigned bmaxu[8];
  __shared__ float xmaxs[8];
  int tid = threadIdx.x;
  int n0 = blockIdx.x * 8;
  if (tid < 8) {
    bmaxu[tid] = 0;
    int n = n0 + tid;
    int s = off[n], t = off[n + 1];
    ag[tid] = seg_sum_bf16(gd, s, t);
    xp[tid] = xrp[n];
    degs[tid] = (float)(t - s);
  }
  __syncthreads();
  if (tid < 160) {
    int o = tid >> 3, nl = tid & 7;
    float v = b1[o] + degs[nl] * b2[o] + ag[nl] * W2[o] + xp[nl] * W1[o];
    float r = fmaxf(v, 0.f);
    xv[nl][o] = r;
    xrn[(n0 + nl) * 20 + o] = r;
  }
  __syncthreads();
  if (tid < 8) {
    float m = 0.f;
#pragma unroll
    for (int c = 0; c < 20; c++) m = fmaxf(m, xv[tid][c]);
    xmaxs[tid] = fmaxf(m, 1e-30f);
  }
  int k = tid;
  float aa[8], bb[8];
  if (k < KM) {
    v2f wab[20];
    float bm = bm1n[k];
#pragma unroll
    for (int c = 0; c < 20; c++) {
      wab[c].x = Wm1n[c * KM + k];
      wab[c].y = Wm1n[(20 + c) * KM + k];
    }
#pragma unroll
    for (int nl = 0; nl < 8; nl++) {
      v2f acc;
      acc.x = bm;
      acc.y = 0.f;
#pragma unroll
      for (int c = 0; c < 20; c++) {
        v2f xc;
        xc.x = xv[nl][c];
        xc.y = xv[nl][c];
        acc += xc * wab[c];
      }
      aa[nl] = acc.x;
      bb[nl] = acc.y;
    }
  }
  float mxb[8];
#pragma unroll
  for (int nl = 0; nl < 8; nl++) mxb[nl] = (k < KM) ? fabsf(bb[nl]) : 0.f;
#pragma unroll
  for (int s = 1; s < 64; s <<= 1) {
#pragma unroll
    for (int nl = 0; nl < 8; nl++) mxb[nl] = fmaxf(mxb[nl], __shfl_xor(mxb[nl], s));
  }
  if ((tid & 63) == 0) {
#pragma unroll
    for (int nl = 0; nl < 8; nl++) atomicMax(&bmaxu[nl], __float_as_uint(mxb[nl]));
  }
  __syncthreads();
  if (k < KM) {
#pragma unroll
    for (int nl = 0; nl < 8; nl++) {
      float bmax = fmaxf(__uint_as_float(bmaxu[nl]), 1e-30f);
      float xmax = xmaxs[nl];
      size_t rowA = (size_t)(n0 + nl) * RS;
      unsigned char* rb = Bq + (size_t)(n0 + nl) * RSB;
      A2[rowA + k] = aa[nl];
      rb[k] = (unsigned char)(signed char)lrintf(bb[nl] * (127.f / bmax));
      if (k < 20) {
        A2[rowA + KM + k] = xv[nl][k];
        ((__half*)(rb + 208))[k] = __float2half(xv[nl][k] * (32768.f / xmax));
      }
      if (k == 0) {
        ((float*)(rb + 248))[0] = bmax / 127.f;
        ((float*)(rb + 248))[1] = xmax / 32768.f;
      }
    }
  }
}

// afp20: after a hidden edge (gd 20-channel bf16). Same 3 phases, CIN=20.
__global__ void __launch_bounds__(256) afp20_kernel(
    const unsigned short* __restrict__ gd, const int* __restrict__ off,
    const float* __restrict__ xrp,
    const float* __restrict__ W1, const float* __restrict__ b1,
    const float* __restrict__ W2, const float* __restrict__ b2,
    const float* __restrict__ Wm1n, const float* __restrict__ bm1n,
    float* __restrict__ A2, unsigned char* __restrict__ Bq, float* __restrict__ xrn) {
  __shared__ float ag[8][21], xp[8][21], xv[8][21], degs[8];
  __shared__ unsigned bmaxu[8];
  __shared__ float xmaxs[8];
  int tid = threadIdx.x;
  int n0 = blockIdx.x * 8;
  if (tid < 8) bmaxu[tid] = 0;
  if (tid < 160) {
    int c = tid >> 3, nl = tid & 7;  // adjacent lanes: same c, adjacent n
    int n = n0 + nl;
    int s = off[n], t = off[n + 1];
    ag[nl][c] = seg_sum_bf16(gd + (size_t)c * E_EDGES, s, t);
    xp[nl][c] = xrp[n * 20 + c];
    if (c == 0) degs[nl] = (float)(t - s);
  }
  __syncthreads();
  if (tid < 160) {
    int o = tid >> 3, nl = tid & 7;
    float v = b1[o] + degs[nl] * b2[o];
#pragma unroll
    for (int c = 0; c < 20; c++) {
      v += ag[nl][c] * W2[c * 20 + o] + xp[nl][c] * W1[c * 20 + o];
    }
    float r = fmaxf(v, 0.f);
    xv[nl][o] = r;
    xrn[(n0 + nl) * 20 + o] = r;
  }
  __syncthreads();
  if (tid < 8) {
    float m = 0.f;
#pragma unroll
    for (int c = 0; c < 20; c++) m = fmaxf(m, xv[tid][c]);
    xmaxs[tid] = fmaxf(m, 1e-30f);
  }
  int k = tid;
  float aa[8], bb[8];
  if (k < KM) {
    v2f wab[20];
    float bm = bm1n[k];
#pragma unroll
    for (int c = 0; c < 20; c++) {
      wab[c].x = Wm1n[c * KM + k];
      wab[c].y = Wm1n[(20 + c) * KM + k];
    }
#pragma unroll
    for (int nl = 0; nl < 8; nl++) {
      v2f acc;
      acc.x = bm;
      acc.y = 0.f;
#pragma unroll
      for (int c = 0; c < 20; c++) {
        v2f xc;
        xc.x = xv[nl][c];
        xc.y = xv[nl][c];
        acc += xc * wab[c];
      }
      aa[nl] = acc.x;
      bb[nl] = acc.y;
    }
  }
  float mxb[8];
#pragma unroll
  for (int nl = 0; nl < 8; nl++) mxb[nl] = (k < KM) ? fabsf(bb[nl]) : 0.f;
#pragma unroll
  for (int s = 1; s < 64; s <<= 1) {
#pragma unroll
    for (int nl = 0; nl < 8; nl++) mxb[nl] = fmaxf(mxb[nl], __shfl_xor(mxb[nl], s));
  }
  if ((tid & 63) == 0) {
#pragma unroll
    for (int nl = 0; nl < 8; nl++) atomicMax(&bmaxu[nl], __float_as_uint(mxb[nl]));
  }
  __syncthreads();
  if (k < KM) {
#pragma unroll
    for (int nl = 0; nl < 8; nl++) {
      float bmax = fmaxf(__uint_as_float(bmaxu[nl]), 1e-30f);
      float xmax = xmaxs[nl];
      size_t rowA = (size_t)(n0 + nl) * RS;
      unsigned char* rb = Bq + (size_t)(n0 + nl) * RSB;
      A2[rowA + k] = aa[nl];
      rb[k] = (unsigned char)(signed char)lrintf(bb[nl] * (127.f / bmax));
      if (k < 20) {
        A2[rowA + KM + k] = xv[nl][k];
        ((__half*)(rb + 208))[k] = __float2half(xv[nl][k] * (32768.f / xmax));
      }
      if (k == 0) {
        ((float*)(rb + 248))[0] = bmax / 127.f;
        ((float*)(rb + 248))[1] = xmax / 32768.f;
      }
    }
  }
}

// ---------------- launch ----------------

extern "C" void kernel_launch(void* const* d_in, const int* in_sizes, int n_in,
                              void* d_out, int out_size, void* d_ws, size_t ws_size,
                              hipStream_t stream) {
  const float* features = (const float*)d_in[0];
  const int* edges = (const int*)d_in[1];
  // d_in[2] = weights (unused by reference)

  const float *dW1 = (const float*)d_in[3], *db1 = (const float*)d_in[4],
              *dWm1 = (const float*)d_in[5], *dbm1 = (const float*)d_in[6],
              *dWm2 = (const float*)d_in[7], *dbm2 = (const float*)d_in[8],
              *dW2 = (const float*)d_in[9], *db2 = (const float*)d_in[10];
  const float *hW1 = (const float*)d_in[11], *hb1 = (const float*)d_in[12],
              *hWm1 = (const float*)d_in[13], *hbm1 = (const float*)d_in[14],
              *hWm2 = (const float*)d_in[15], *hbm2 = (const float*)d_in[16],
              *hW2 = (const float*)d_in[17], *hb2 = (const float*)d_in[18];
  const float *oW1 = (const float*)d_in[19], *ob1 = (const float*)d_in[20],
              *oWm1 = (const float*)d_in[21], *obm1 = (const float*)d_in[22],
              *oWm2 = (const float*)d_in[23], *obm2 = (const float*)d_in[24],
              *oW2 = (const float*)d_in[25], *ob2 = (const float*)d_in[26];

  // workspace layout (float units)
  float* fws = (float*)d_ws;
  size_t o = 0;
  float* A2 = fws + o;                           o += (size_t)N_NODES * RS;       // 5.6M
  unsigned char* Bq = (unsigned char*)(fws + o); o += (size_t)N_NODES * RSB / 4;  // 1.6M floats
  unsigned short* gd = (unsigned short*)(fws + o); o += (size_t)20 * E_EDGES / 2; // 4.0M floats (bf16)
  float* xrA = fws + o;                          o += (size_t)N_NODES * 20;
  float* xrB = fws + o;                          o += (size_t)N_NODES * 20;
  int* ip = (int*)(fws + o);
  int* hist = ip;   ip += N_NODES;
  int* off = ip;    ip += N_NODES + 4;
  int* cursor = ip; ip += N_NODES;
  int2* se = (int2*)ip;

  const int B256 = 256;
  const int EDGE_G = E_EDGES / 128;  // 3125, exact (128-thread blocks, 1 thread/edge)
  const int NODE8_G = N_NODES / 8;   // 3125, exact

  // build dst-sorted edge list + CSR offsets (recomputed every launch)
  (void)hipMemsetAsync(hist, 0, N_NODES * sizeof(int), stream);
  hist_kernel<<<(E_EDGES + B256 - 1) / B256, B256, 0, stream>>>(edges, hist);
  scan_kernel<<<1, 1024, 0, stream>>>(hist, off, cursor);

  // layer d: 1 -> 20 (scatter + d_out zeroing fused into prep)
  scatter_prep_d_kernel<<<NODE8_G, B256, 0, stream>>>(edges, cursor, se, features,
                                                      dWm1, dbm1, A2, Bq, xrA,
                                                      (float*)d_out);
  edge_kernel<1><<<EDGE_G, 128, 0, stream>>>(se, A2, Bq, dWm2, dbm2, gd);
  afp1_kernel<<<NODE8_G, B256, 0, stream>>>(gd, off, xrA, dW1, db1, dW2, db2,
                                            hWm1, hbm1, A2, Bq, xrB);

  // hidden1
  edge_kernel<20><<<EDGE_G, 128, 0, stream>>>(se, A2, Bq, hWm2, hbm2, gd);
  afp20_kernel<<<NODE8_G, B256, 0, stream>>>(gd, off, xrB, hW1, hb1, hW2, hb2,
                                             hWm1, hbm1, A2, Bq, xrA);
  // hidden2
  edge_kernel<20><<<EDGE_G, 128, 0, stream>>>(se, A2, Bq, hWm2, hbm2, gd);
  afp20_kernel<<<NODE8_G, B256, 0, stream>>>(gd, off, xrA, hW1, hb1, hW2, hb2,
                                             hWm1, hbm1, A2, Bq, xrB);
  // hidden3 -> preps output layer (oWm1)
  edge_kernel<20><<<EDGE_G, 128, 0, stream>>>(se, A2, Bq, hWm2, hbm2, gd);
  afp20_kernel<<<NODE8_G, B256, 0, stream>>>(gd, off, xrB, hW1, hb1, hW2, hb2,
                                             oWm1, obm1, A2, Bq, xrA);
  // output layer: 20 -> 1, gd-free (scalar atomics into d_out) + node terms fused
  edge_final_kernel<<<EDGE_G, 128, 0, stream>>>(se, A2, Bq, oWm2, obm2, oW2,
                                                off, xrA, oW1, ob1, ob2,
                                                (float*)d_out);
}